// Round 2
// baseline (61.885 us; speedup 1.0000x reference)
//
#include <hip/hip_runtime.h>

#define IMGS 32
#define H 512
#define W 512
#define NPIX (H * W)            // 262144
#define NTHR 256

// K1: gray -> combined 9-pt stencil -> pre-norm value s.
// Writes s into out channel-0 plane (scratch); per-block (sum, sumsq) to ws.
// Grid: 32 images * 32 blocks = 1024 blocks; each block does two 64x64 tiles.
__global__ __launch_bounds__(NTHR) void k1_stencil(
    const float* __restrict__ x, float* __restrict__ out,
    float2* __restrict__ partials)
{
    __shared__ float G[66][67];          // gray halo tile, +1 pad on stride
    __shared__ float wsum[4], wsq[4];

    const int tid = threadIdx.x;
    const int blk = blockIdx.x;
    const int img = blk >> 5;
    const int blkInImg = blk & 31;

    const float c0 = 1.0f / 15.0f, c1 = 2.0f / 15.0f;
    const float c2 = 4.0f / 15.0f, c3 = 8.0f / 15.0f;

    const float* xbase = x + (size_t)img * 3 * NPIX;
    float* sbase = out + (size_t)img * 3 * NPIX;   // channel-0 plane as scratch

    const int col  = tid & 63;
    const int row0 = tid >> 6;

    float sum = 0.0f, sq = 0.0f;

    for (int tt = 0; tt < 2; ++tt) {
        const int t  = 2 * blkInImg + tt;      // tile 0..63 (8x8 tiles of 64x64)
        const int tr = (t >> 3) * 64;
        const int tc = (t & 7) * 64;

        __syncthreads();                       // guard G reuse across tiles
        for (int idx = tid; idx < 66 * 66; idx += NTHR) {
            const int gi = idx / 66;
            const int gj = idx - gi * 66;
            const int y  = tr - 1 + gi;
            const int xx = tc - 1 + gj;
            float gval = 0.0f;
            if ((unsigned)y < (unsigned)H && (unsigned)xx < (unsigned)W) {
                const int off = y * W + xx;
                gval = fmaf(0.3f, xbase[off],
                       fmaf(0.59f, xbase[NPIX + off],
                            0.11f * xbase[2 * NPIX + off]));
            }
            G[gi][gj] = gval;
        }
        __syncthreads();

#pragma unroll
        for (int k = 0; k < 16; ++k) {
            const int r = 4 * k + row0;
            const float gC = G[r + 1][col + 1];
            const float Lv = G[r + 1][col],     Rv = G[r + 1][col + 2];
            const float Uv = G[r][col + 1],     Dv = G[r + 2][col + 1];
            const float UL = G[r][col],         UR = G[r][col + 2];
            const float DL = G[r + 2][col],     DR = G[r + 2][col + 2];
            const float acc = c0 * (Lv + Rv) + c1 * (UR + DL) +
                              c2 * (Uv + Dv) + c3 * (UL + DR);
            const float s = 0.5f * (gC - 0.5f * acc) + 0.5f;
            sbase[(tr + r) * W + tc + col] = s;
            sum += s;
            sq = fmaf(s, s, sq);
        }
    }

    // Block reduction: 64-lane shuffle tree, then 4 wave leaders via LDS.
#pragma unroll
    for (int off = 32; off > 0; off >>= 1) {
        sum += __shfl_down(sum, off);
        sq  += __shfl_down(sq, off);
    }
    const int wave = tid >> 6;
    const int lane = tid & 63;
    if (lane == 0) { wsum[wave] = sum; wsq[wave] = sq; }
    __syncthreads();
    if (tid == 0) {
        partials[blk] = make_float2(wsum[0] + wsum[1] + wsum[2] + wsum[3],
                                    wsq[0] + wsq[1] + wsq[2] + wsq[3]);
    }
}

// K2: per-image stats from partials (block-redundant, L2-resident), then
// normalize channel-0 plane and replicate to 3 channels, float4-vectorized.
// Grid: 32 images * 256 blocks = 8192 blocks; 1024 px per block.
__global__ __launch_bounds__(NTHR) void k2_norm(
    const float2* __restrict__ partials, float* __restrict__ out)
{
    __shared__ float sm[2];

    const int tid = threadIdx.x;
    const int blk = blockIdx.x;
    const int img = blk >> 8;
    const int bi  = blk & 255;

    if (tid < 64) {
        float2 p = (tid < 32) ? partials[img * 32 + tid]
                              : make_float2(0.0f, 0.0f);
        float S1 = p.x, S2 = p.y;
#pragma unroll
        for (int off = 16; off > 0; off >>= 1) {
            S1 += __shfl_down(S1, off);
            S2 += __shfl_down(S2, off);
        }
        if (tid == 0) {
            const float m = S1 * (1.0f / NPIX);
            const float v = S2 * (1.0f / NPIX) - m * m;
            sm[0] = m;
            sm[1] = rsqrtf(v + 1e-5f);
        }
    }
    __syncthreads();
    const float mean = sm[0];
    const float rstd = sm[1];

    float* base = out + (size_t)img * 3 * NPIX;
    const int off = (bi * NTHR + tid) * 4;     // float4-aligned pixel offset

    float4 v = *(const float4*)(base + off);
    v.x = (v.x - mean) * rstd;
    v.y = (v.y - mean) * rstd;
    v.z = (v.z - mean) * rstd;
    v.w = (v.w - mean) * rstd;
    *(float4*)(base + off) = v;
    *(float4*)(base + NPIX + off) = v;
    *(float4*)(base + 2 * NPIX + off) = v;
}

extern "C" void kernel_launch(void* const* d_in, const int* in_sizes, int n_in,
                              void* d_out, int out_size, void* d_ws, size_t ws_size,
                              hipStream_t stream) {
    const float* x = (const float*)d_in[0];
    float* out = (float*)d_out;
    float2* partials = (float2*)d_ws;   // 1024 * 8 B = 8 KiB

    k1_stencil<<<dim3(IMGS * 32), dim3(NTHR), 0, stream>>>(x, out, partials);
    k2_norm<<<dim3(IMGS * 256), dim3(NTHR), 0, stream>>>(partials, out);
}

// Round 3
// 45.747 us; speedup vs baseline: 1.3528x; 1.3528x over previous
//
#include <hip/hip_runtime.h>
#include <hip/hip_fp16.h>

#define IMGS 32
#define H 512
#define W 512
#define NPIX (H * W)            // 262144
#define NTHR 256
#define RB 8                    // rows per band
#define NBANDS (H / RB)         // 64 bands per image
#define C4W (W / 4)             // 128 float4 per row

// Combined 9-pt stencil: s = 0.5*g - 0.25*(c0(L+R)+c1(UR+DL)+c2(U+D)+c3(UL+DR)) + 0.5
__device__ __forceinline__ float sten(float C, float L, float R, float U, float D,
                                      float UL, float UR, float DL, float DR) {
    const float c0 = 1.0f / 15.0f, c1 = 2.0f / 15.0f;
    const float c2 = 4.0f / 15.0f, c3 = 8.0f / 15.0f;
    const float acc = c0 * (L + R) + c1 * (UR + DL) + c2 * (U + D) + c3 * (UL + DR);
    return fmaf(-0.25f, acc, fmaf(0.5f, C, 0.5f));
}

// K1: full-width 512x8 band per block (grid = 32*64 = 2048 blocks).
// Stage 10 gray rows in LDS via coalesced float4 loads; stencil via
// register-rolling rows; write s (fp16 in ws, or fp32 fallback); per-block
// (sum, sumsq) partial to `partials`.
template <typename ST>
__global__ __launch_bounds__(NTHR, 6) void k1_stencil(
    const float* __restrict__ x, ST* sout, size_t sstride,
    float2* __restrict__ partials)
{
    __shared__ float G[RB + 2][W];       // 10 x 512 x 4B = 20 KB

    const int tid  = threadIdx.x;
    const int blk  = blockIdx.x;
    const int img  = blk >> 6;           // / NBANDS
    const int band = blk & (NBANDS - 1);
    const int r0   = band * RB;

    const float* xbase = x + (size_t)img * 3 * NPIX;
    ST* sbase = sout + (size_t)img * sstride;

    // ---- stage gray halo rows r0-1 .. r0+8 (zero outside image) ----
#pragma unroll
    for (int it = 0; it < (RB + 2) * C4W / NTHR; ++it) {   // 5 iterations
        const int idx = it * NTHR + tid;                   // 0..1279
        const int ri  = idx >> 7;                          // 0..9
        const int c4  = idx & (C4W - 1);
        const int gr  = r0 - 1 + ri;
        float4 g4 = make_float4(0.f, 0.f, 0.f, 0.f);
        if ((unsigned)gr < (unsigned)H) {
            const float* p = xbase + gr * W + c4 * 4;
            const float4 r = *(const float4*)p;
            const float4 g = *(const float4*)(p + NPIX);
            const float4 b = *(const float4*)(p + 2 * NPIX);
            g4.x = fmaf(0.3f, r.x, fmaf(0.59f, g.x, 0.11f * b.x));
            g4.y = fmaf(0.3f, r.y, fmaf(0.59f, g.y, 0.11f * b.y));
            g4.z = fmaf(0.3f, r.z, fmaf(0.59f, g.z, 0.11f * b.z));
            g4.w = fmaf(0.3f, r.w, fmaf(0.59f, g.w, 0.11f * b.w));
        }
        *(float4*)&G[ri][c4 * 4] = g4;
    }
    __syncthreads();

    // ---- compute: thread = (half, c4); RB/2 rows per thread, rolling ----
    const int c4   = tid & (C4W - 1);
    const int half = tid >> 7;                 // 0..1
    const int lr0  = half * (RB / 2);          // first LDS "above" row

    float sum = 0.0f, sq = 0.0f;

    float4 a4 = *(const float4*)&G[lr0][c4 * 4];
    float4 b4 = *(const float4*)&G[lr0 + 1][c4 * 4];
    float aL = (c4 == 0) ? 0.0f : G[lr0][c4 * 4 - 1];
    float aR = (c4 == C4W - 1) ? 0.0f : G[lr0][c4 * 4 + 4];
    float bL = (c4 == 0) ? 0.0f : G[lr0 + 1][c4 * 4 - 1];
    float bR = (c4 == C4W - 1) ? 0.0f : G[lr0 + 1][c4 * 4 + 4];

#pragma unroll
    for (int k = 0; k < RB / 2; ++k) {
        const int lr = lr0 + k + 2;            // row below
        const float4 d4 = *(const float4*)&G[lr][c4 * 4];
        const float dL = (c4 == 0) ? 0.0f : G[lr][c4 * 4 - 1];
        const float dR = (c4 == C4W - 1) ? 0.0f : G[lr][c4 * 4 + 4];

        float4 o;
        o.x = sten(b4.x, bL,   b4.y, a4.x, d4.x, aL,   a4.y, dL,   d4.y);
        o.y = sten(b4.y, b4.x, b4.z, a4.y, d4.y, a4.x, a4.z, d4.x, d4.z);
        o.z = sten(b4.z, b4.y, b4.w, a4.z, d4.z, a4.y, a4.w, d4.y, d4.w);
        o.w = sten(b4.w, b4.z, bR,   a4.w, d4.w, a4.z, aR,   d4.z, dR);

        sum += (o.x + o.y) + (o.z + o.w);
        sq = fmaf(o.x, o.x, sq); sq = fmaf(o.y, o.y, sq);
        sq = fmaf(o.z, o.z, sq); sq = fmaf(o.w, o.w, sq);

        const size_t off = (size_t)(r0 + half * (RB / 2) + k) * W + c4 * 4;
        if constexpr (sizeof(ST) == 2) {
            union { __half h[4]; float2 f; } u;
            u.h[0] = __float2half_rn(o.x);
            u.h[1] = __float2half_rn(o.y);
            u.h[2] = __float2half_rn(o.z);
            u.h[3] = __float2half_rn(o.w);
            *(float2*)(sbase + off) = u.f;
        } else {
            *(float4*)(sbase + off) = o;
        }

        a4 = b4; aL = bL; aR = bR;
        b4 = d4; bL = dL; bR = dR;
    }

    // ---- block reduction (reuse G row 0 after all reads complete) ----
#pragma unroll
    for (int off = 32; off > 0; off >>= 1) {
        sum += __shfl_down(sum, off);
        sq  += __shfl_down(sq, off);
    }
    __syncthreads();                           // all LDS reads done
    const int wave = tid >> 6;
    const int lane = tid & 63;
    if (lane == 0) { G[0][wave] = sum; G[0][4 + wave] = sq; }
    __syncthreads();
    if (tid == 0) {
        partials[blk] = make_float2((G[0][0] + G[0][1]) + (G[0][2] + G[0][3]),
                                    (G[0][4] + G[0][5]) + (G[0][6] + G[0][7]));
    }
}

// K2: per-image stats from the 64 band partials (block-redundant, L2-resident),
// then normalize s and replicate to 3 fp32 channels, float4-vectorized.
// Grid: 32 images * 256 blocks; 1024 px per block.
template <typename ST>
__global__ __launch_bounds__(NTHR) void k2_norm(
    const float2* __restrict__ partials, const ST* sin, size_t sstride,
    float* __restrict__ out)
{
    __shared__ float sm[2];

    const int tid = threadIdx.x;
    const int blk = blockIdx.x;
    const int img = blk >> 8;
    const int bi  = blk & 255;

    if (tid < 64) {
        const float2 p = partials[img * NBANDS + tid];   // NBANDS == 64
        float S1 = p.x, S2 = p.y;
#pragma unroll
        for (int off = 32; off > 0; off >>= 1) {
            S1 += __shfl_down(S1, off);
            S2 += __shfl_down(S2, off);
        }
        if (tid == 0) {
            const float m = S1 * (1.0f / NPIX);
            const float v = S2 * (1.0f / NPIX) - m * m;
            sm[0] = m;
            sm[1] = rsqrtf(v + 1e-5f);
        }
    }
    __syncthreads();
    const float mean = sm[0];
    const float rstd = sm[1];

    const ST* sb = sin + (size_t)img * sstride;
    float* base = out + (size_t)img * 3 * NPIX;
    const size_t off = (size_t)(bi * NTHR + tid) * 4;

    float4 v;
    if constexpr (sizeof(ST) == 2) {
        union { float2 f; __half h[4]; } u;
        u.f = *(const float2*)(sb + off);
        v.x = __half2float(u.h[0]); v.y = __half2float(u.h[1]);
        v.z = __half2float(u.h[2]); v.w = __half2float(u.h[3]);
    } else {
        v = *(const float4*)(sb + off);
    }
    v.x = (v.x - mean) * rstd;
    v.y = (v.y - mean) * rstd;
    v.z = (v.z - mean) * rstd;
    v.w = (v.w - mean) * rstd;
    *(float4*)(base + off) = v;
    *(float4*)(base + NPIX + off) = v;
    *(float4*)(base + 2 * NPIX + off) = v;
}

extern "C" void kernel_launch(void* const* d_in, const int* in_sizes, int n_in,
                              void* d_out, int out_size, void* d_ws, size_t ws_size,
                              hipStream_t stream) {
    const float* x = (const float*)d_in[0];
    float* out = (float*)d_out;

    const size_t s_bytes = (size_t)IMGS * NPIX * sizeof(__half);   // 16 MiB
    const size_t need = s_bytes + (size_t)IMGS * NBANDS * sizeof(float2);

    if (ws_size >= need) {
        __half* s = (__half*)d_ws;
        float2* partials = (float2*)((char*)d_ws + s_bytes);
        k1_stencil<__half><<<dim3(IMGS * NBANDS), dim3(NTHR), 0, stream>>>(
            x, s, (size_t)NPIX, partials);
        k2_norm<__half><<<dim3(IMGS * 256), dim3(NTHR), 0, stream>>>(
            partials, s, (size_t)NPIX, out);
    } else {
        // Fallback: fp32 s in out channel-0 plane (round-2 proven path).
        float2* partials = (float2*)d_ws;                          // 16 KiB
        k1_stencil<float><<<dim3(IMGS * NBANDS), dim3(NTHR), 0, stream>>>(
            x, out, (size_t)(3 * NPIX), partials);
        k2_norm<float><<<dim3(IMGS * 256), dim3(NTHR), 0, stream>>>(
            partials, out, (size_t)(3 * NPIX), out);
    }
}